// Round 2
// baseline (343.823 us; speedup 1.0000x reference)
//
#include <hip/hip_runtime.h>

// CASSI forward: Y[b,m,no] = sum_l H[m,no-l] * x[b,m,no-l,l], no in [0,542)
// then Y /= max(Y); output = [Y flat | H flat].
// B=8, M=512, L=31, S=1.
//
// Strategy: one block per (b,m) row. Lanes read the x row STRIDE-1 COALESCED
// (the only coalescible axis is the innermost l), compute H[n]*x, and
// scatter-add into a 542-float LDS accumulator at column n+l via ds_add_f32.
// Consecutive-lane element mapping gives <=3-way same-address collisions
// (col(e)=e/31+e%31 repeats only at deltas 30/60). Index math is incremental.

#define MDIM   512
#define LBANDS 31
#define WOUT   (MDIM + LBANDS - 1)   // 542
#define BATCH  8
#define ROWELEMS (MDIM * LBANDS)     // 15872, == 62 * 256 exactly

__global__ __launch_bounds__(256) void cassi_scatter_kernel(
    const float* __restrict__ x,      // (B, M, M, L)
    const float* __restrict__ Hm,     // (M, M)
    float* __restrict__ Y,            // (B, M, WOUT)
    unsigned int* __restrict__ gmax)  // 1 uint in d_ws, pre-zeroed
{
    __shared__ float yacc[WOUT];
    __shared__ float smax[4];

    const int tid = threadIdx.x;
    const int bm  = blockIdx.x;           // b*M + m
    const int m   = bm & (MDIM - 1);

    for (int i = tid; i < WOUT; i += 256) yacc[i] = 0.0f;
    __syncthreads();

    const float* __restrict__ xrow = x + (long long)bm * ROWELEMS;
    const float* __restrict__ hrow = Hm + m * MDIM;

    // e = tid + 256*k, k = 0..61. Maintain n = e/31, l = e%31 incrementally:
    // delta 256 = 8*31 + 8 -> n += 8, l += 8, wrap once if l >= 31.
    int n = tid / 31;           // tid < 256, cheap magic-div once
    int l = tid - n * 31;

    #pragma unroll 4
    for (int k = 0; k < ROWELEMS / 256; ++k) {
        const float v = xrow[tid + (k << 8)];     // stride-1 coalesced b32
        const float a = hrow[n] * v;              // H broadcast, L1-resident
        atomicAdd(&yacc[n + l], a);               // ds_add_f32
        n += 8; l += 8;
        if (l >= LBANDS) { l -= LBANDS; ++n; }
    }
    __syncthreads();

    // Write out the row + block max reduction (all values >= 0).
    float lmax = 0.0f;
    float* __restrict__ yout = Y + (long long)bm * WOUT;
    for (int c = tid; c < WOUT; c += 256) {
        const float v = yacc[c];
        yout[c] = v;
        lmax = fmaxf(lmax, v);
    }
    #pragma unroll
    for (int off = 32; off > 0; off >>= 1)
        lmax = fmaxf(lmax, __shfl_down(lmax, off, 64));
    const int lane = tid & 63;
    const int wid  = tid >> 6;
    if (lane == 0) smax[wid] = lmax;
    __syncthreads();
    if (tid == 0) {
        const float bmax = fmaxf(fmaxf(smax[0], smax[1]), fmaxf(smax[2], smax[3]));
        // uint-ordered atomicMax is float-ordered for non-negative floats
        atomicMax(gmax, __float_as_uint(bmax));
    }
}

__global__ __launch_bounds__(256) void cassi_normalize_kernel(
    const float* __restrict__ Hm,             // (M, M) input
    float* __restrict__ out,                  // [Y | H]
    const unsigned int* __restrict__ gmax,
    int ysize, int total)
{
    const int idx = blockIdx.x * blockDim.x + threadIdx.x;
    if (idx >= total) return;
    const float inv = 1.0f / __uint_as_float(*gmax);
    if (idx < ysize) {
        out[idx] *= inv;
    } else {
        out[idx] = Hm[idx - ysize];
    }
}

extern "C" void kernel_launch(void* const* d_in, const int* in_sizes, int n_in,
                              void* d_out, int out_size, void* d_ws, size_t ws_size,
                              hipStream_t stream) {
    const float* x  = (const float*)d_in[0];   // (8, 512, 512, 31, 1)
    const float* Hm = (const float*)d_in[1];   // (1, 512, 512, 1, 1)
    float* out = (float*)d_out;                // [Y (8*512*542) | H (512*512)]
    unsigned int* gmax = (unsigned int*)d_ws;

    const int ysize = BATCH * MDIM * WOUT;     // 2,220,032
    const int total = out_size;                // ysize + 512*512

    // d_ws is poisoned (0xAA) and never re-poisoned: zero the max accumulator
    // every call (async memset is graph-capture safe).
    hipMemsetAsync(d_ws, 0, sizeof(unsigned int), stream);

    cassi_scatter_kernel<<<BATCH * MDIM, 256, 0, stream>>>(x, Hm, out, gmax);
    cassi_normalize_kernel<<<(total + 255) / 256, 256, 0, stream>>>(
        Hm, out, gmax, ysize, total);
}

// Round 3
// 122.923 us; speedup vs baseline: 2.7971x; 2.7971x over previous
//
#include <hip/hip_runtime.h>

// CASSI forward: Y[b,m,no] = sum_l H[m,no-l] * x[b,m,no-l,l], no in [0,542)
// then Y /= max(Y); output = [Y flat | H flat].  B=8, M=512, L=31, S=1.
//
// One block per (b,m) row:
//   1) stage x row (15,872 f = 62KB) into LDS via coalesced float4 loads
//   2) each thread gathers 31 taps/col from LDS; x-gather lane stride = 31
//      floats, gcd(31,32)=1 -> bank-conflict-free. Interior cols (30..511)
//      use a fully unrolled 31-tap loop with immediate ds offsets.
//   3) register max -> shuffle -> one atomicMax per block. NO data atomics.

#define MDIM   512
#define LBANDS 31
#define WOUT   (MDIM + LBANDS - 1)   // 542
#define BATCH  8
#define ROWELEMS (MDIM * LBANDS)     // 15872 floats = 62 KB

__global__ __launch_bounds__(256) void cassi_row_kernel(
    const float* __restrict__ x,      // (B, M, M, L)
    const float* __restrict__ Hm,     // (M, M)
    float* __restrict__ Y,            // (B, M, WOUT)
    unsigned int* __restrict__ gmax)  // 1 uint in d_ws, pre-zeroed
{
    __shared__ float xs[ROWELEMS];    // 63,488 B
    __shared__ float smax[4];

    const int tid = threadIdx.x;
    const int bm  = blockIdx.x;            // b*M + m
    const int m   = bm & (MDIM - 1);

    const float*  __restrict__ xrow = x + (size_t)bm * ROWELEMS;
    const float*  __restrict__ hrow = Hm + m * MDIM;

    // ---- stage x row: 3968 float4, coalesced ----
    const float4* __restrict__ xr4 = (const float4*)xrow;
    float4* xs4 = (float4*)xs;
    for (int i = tid; i < ROWELEMS / 4; i += 256)
        xs4[i] = xr4[i];
    __syncthreads();

    // ---- gather phase: thread owns cols tid, tid+256, (tid<30: tid+512) ----
    float lmax = 0.0f;
    float* __restrict__ yout = Y + (size_t)bm * WOUT;

    for (int no = tid; no < WOUT; no += 256) {
        float acc = 0.0f;
        if (no >= LBANDS - 1 && no < MDIM) {
            // interior: all 31 taps, unrolled, ascending immediate offsets
            const int xbase = no * 31 - 30 * (LBANDS - 1);  // = no*31 - 900
            const int hbase = no - (LBANDS - 1);
            #pragma unroll
            for (int t = 0; t < LBANDS; ++t)               // t = 30 - l
                acc = fmaf(hrow[hbase + t], xs[xbase + 30 * t], acc);
        } else {
            int l0 = no - (MDIM - 1); if (l0 < 0) l0 = 0;
            int l1 = (no < LBANDS - 1) ? no : (LBANDS - 1);
            int xa = no * 31 - 30 * l0;   // (no-l)*31 + l
            int ha = no - l0;
            for (int l = l0; l <= l1; ++l) {
                acc = fmaf(hrow[ha], xs[xa], acc);
                xa -= 30; --ha;
            }
        }
        yout[no] = acc;
        lmax = fmaxf(lmax, acc);
    }

    // ---- block max -> one global atomic ----
    #pragma unroll
    for (int off = 32; off > 0; off >>= 1)
        lmax = fmaxf(lmax, __shfl_down(lmax, off, 64));
    const int lane = tid & 63;
    const int wid  = tid >> 6;
    if (lane == 0) smax[wid] = lmax;
    __syncthreads();
    if (tid == 0) {
        const float bmax = fmaxf(fmaxf(smax[0], smax[1]), fmaxf(smax[2], smax[3]));
        // uint-ordered atomicMax == float-ordered for non-negative floats
        atomicMax(gmax, __float_as_uint(bmax));
    }
}

__global__ __launch_bounds__(256) void cassi_normalize_kernel(
    const float* __restrict__ Hm,             // (M, M) input
    float* __restrict__ out,                  // [Y | H]
    const unsigned int* __restrict__ gmax,
    int ysize, int total)
{
    const int idx = blockIdx.x * blockDim.x + threadIdx.x;
    if (idx >= total) return;
    const float inv = 1.0f / __uint_as_float(*gmax);
    if (idx < ysize) {
        out[idx] *= inv;
    } else {
        out[idx] = Hm[idx - ysize];
    }
}

extern "C" void kernel_launch(void* const* d_in, const int* in_sizes, int n_in,
                              void* d_out, int out_size, void* d_ws, size_t ws_size,
                              hipStream_t stream) {
    const float* x  = (const float*)d_in[0];   // (8, 512, 512, 31, 1)
    const float* Hm = (const float*)d_in[1];   // (1, 512, 512, 1, 1)
    float* out = (float*)d_out;                // [Y (8*512*542) | H (512*512)]
    unsigned int* gmax = (unsigned int*)d_ws;

    const int ysize = BATCH * MDIM * WOUT;     // 2,220,032
    const int total = out_size;                // ysize + 512*512

    // d_ws is poisoned (0xAA) and never re-poisoned: zero the max accumulator
    // every call (async memset is graph-capture safe).
    hipMemsetAsync(d_ws, 0, sizeof(unsigned int), stream);

    cassi_row_kernel<<<BATCH * MDIM, 256, 0, stream>>>(x, Hm, out, gmax);
    cassi_normalize_kernel<<<(total + 255) / 256, 256, 0, stream>>>(
        Hm, out, gmax, ysize, total);
}

// Round 4
// 85.802 us; speedup vs baseline: 4.0072x; 1.4326x over previous
//
#include <hip/hip_runtime.h>
#include <stdint.h>

// CASSI forward: Y[b,m,no] = sum_l H[m,no-l] * x[b,m,no-l,l], no in [0,542)
// then Y /= max(Y); output = [Y flat | H flat].  B=8, M=512, L=31, S=1.
//
// R4 structure: 4 column-chunks per (b,m) row (136 cols each) so the staged
// x slice is only ~20.6KB -> 7 blocks/CU (87% occupancy, vs 21% at full-row).
// Staging uses global_load_lds width=16 (fire-and-forget DMA, no VGPR
// round-trip). LDS gather lane-stride = 31 floats, coprime with 32 banks ->
// conflict-free. Per-block max goes to ws[] (no global atomic contention);
// a 1-block reduce kernel computes 1/max; normalize applies it + appends H.

#define MDIM    512
#define LBANDS  31
#define WOUT    (MDIM + LBANDS - 1)    // 542
#define BATCH   8
#define ROWELEMS (MDIM * LBANDS)       // 15872
#define CHUNK   136
#define NCHUNK  4                      // 4*136 = 544 >= 542
#define NBLK    (BATCH * MDIM * NCHUNK) // 16384
#define MAXVEC  1288                   // max float4 slots per slice (<=1287 used)

__global__ __launch_bounds__(256) void cassi_fwd_kernel(
    const float* __restrict__ x,      // (B, M, M, L)
    const float* __restrict__ Hm,     // (M, M)
    float* __restrict__ Y,            // (B, M, WOUT)
    float* __restrict__ bmaxs)        // per-block max, ws[1..NBLK]
{
    __shared__ float xs[MAXVEC * 4];  // 20,608 B
    __shared__ float smax[4];

    const int tid = threadIdx.x;
    const int p   = blockIdx.x;
    // XCD-aware swizzle (bijective: 16384 % 8 == 0): keeps a row's adjacent,
    // slice-overlapping chunks on the same XCD's L2.
    const int lb    = ((p & 7) << 11) + (p >> 3);
    const int bm    = lb >> 2;             // b*M + m
    const int chunk = lb & 3;
    const int c0    = chunk * CHUNK;
    const int m     = bm & (MDIM - 1);

    // x slice needed for cols [c0, c0+ncols): n in [n0, n1]
    const int n0   = (c0 - (LBANDS - 1)) > 0 ? (c0 - (LBANDS - 1)) : 0;
    const int n1   = (c0 + CHUNK - 1) < (MDIM - 1) ? (c0 + CHUNK - 1) : (MDIM - 1);
    const int gb   = (n0 * LBANDS) & ~3;        // 16B-aligned float base
    const int endf = (n1 + 1) * LBANDS;         // exclusive float end
    const int nvec = (endf - gb + 3) >> 2;      // float4 count (verified: never
                                                //  overruns the x row)

    // ---- stage slice via global->LDS DMA, linear, coalesced ----
    const float* __restrict__ xsl = x + (size_t)bm * ROWELEMS + gb;
    for (int i = tid; i < nvec; i += 256) {
        __builtin_amdgcn_global_load_lds(
            (const __attribute__((address_space(1))) void*)(xsl + 4 * i),
            (__attribute__((address_space(3))) void*)(xs + 4 * i),
            16, 0, 0);
    }
    __syncthreads();   // drains vmcnt before LDS reads

    // ---- gather: thread tid owns col c0+tid ----
    const int ncols = (WOUT - c0) < CHUNK ? (WOUT - c0) : CHUNK;
    float lmax = 0.0f;
    if (tid < ncols) {
        const int no = c0 + tid;
        const float* __restrict__ hrow = Hm + m * MDIM;
        int l0 = no - (MDIM - 1); if (l0 < 0) l0 = 0;
        const int l1 = (no < LBANDS - 1) ? no : (LBANDS - 1);
        int e = (no - l0) * LBANDS + l0 - gb;   // LDS index; lane stride 31 ->
        int h = no - l0;                        // conflict-free banks
        float acc = 0.0f;
        for (int l = l0; l <= l1; ++l) {
            acc = fmaf(hrow[h], xs[e], acc);
            e -= (LBANDS - 1);
            --h;
        }
        Y[(size_t)bm * WOUT + no] = acc;
        lmax = acc;
    }

    // ---- block max -> ws slot (no global atomic) ----
    #pragma unroll
    for (int off = 32; off > 0; off >>= 1)
        lmax = fmaxf(lmax, __shfl_down(lmax, off, 64));
    const int lane = tid & 63;
    const int wid  = tid >> 6;
    if (lane == 0) smax[wid] = lmax;
    __syncthreads();
    if (tid == 0)
        bmaxs[p] = fmaxf(fmaxf(smax[0], smax[1]), fmaxf(smax[2], smax[3]));
}

__global__ __launch_bounds__(256) void cassi_reduce_kernel(
    const float* __restrict__ bmaxs,  // NBLK floats
    float* __restrict__ ginv)         // ws[0] <- 1/max
{
    __shared__ float smax[4];
    float lmax = 0.0f;
    for (int i = threadIdx.x; i < NBLK; i += 256)
        lmax = fmaxf(lmax, bmaxs[i]);
    #pragma unroll
    for (int off = 32; off > 0; off >>= 1)
        lmax = fmaxf(lmax, __shfl_down(lmax, off, 64));
    const int lane = threadIdx.x & 63;
    const int wid  = threadIdx.x >> 6;
    if (lane == 0) smax[wid] = lmax;
    __syncthreads();
    if (threadIdx.x == 0)
        ginv[0] = 1.0f / fmaxf(fmaxf(smax[0], smax[1]), fmaxf(smax[2], smax[3]));
}

__global__ __launch_bounds__(256) void cassi_normalize_kernel(
    const float* __restrict__ Hm,             // (M, M) input
    float* __restrict__ out,                  // [Y | H]
    const float* __restrict__ ginv,
    int ysize, int total)
{
    const int idx = blockIdx.x * blockDim.x + threadIdx.x;
    if (idx >= total) return;
    const float inv = ginv[0];
    if (idx < ysize) {
        out[idx] *= inv;
    } else {
        out[idx] = Hm[idx - ysize];
    }
}

extern "C" void kernel_launch(void* const* d_in, const int* in_sizes, int n_in,
                              void* d_out, int out_size, void* d_ws, size_t ws_size,
                              hipStream_t stream) {
    const float* x  = (const float*)d_in[0];   // (8, 512, 512, 31, 1)
    const float* Hm = (const float*)d_in[1];   // (1, 512, 512, 1, 1)
    float* out = (float*)d_out;                // [Y (8*512*542) | H (512*512)]
    float* ws  = (float*)d_ws;                 // ws[0]=1/max, ws[1..]=block maxes

    const int ysize = BATCH * MDIM * WOUT;     // 2,220,032
    const int total = out_size;                // ysize + 512*512

    cassi_fwd_kernel<<<NBLK, 256, 0, stream>>>(x, Hm, out, ws + 1);
    cassi_reduce_kernel<<<1, 256, 0, stream>>>(ws + 1, ws);
    cassi_normalize_kernel<<<(total + 255) / 256, 256, 0, stream>>>(
        Hm, out, ws, ysize, total);
}